// Round 1
// 230.301 us; speedup vs baseline: 1.0821x; 1.0821x over previous
//
#include <hip/hip_runtime.h>
#include <math.h>

#define H_DIM 128
#define OUT_DIM 10

typedef __attribute__((ext_vector_type(8))) __bf16 bf16x8;
typedef __attribute__((ext_vector_type(8))) unsigned short ushort8;
typedef __attribute__((ext_vector_type(4))) float f32x4;

__device__ inline unsigned short f2bf_rne(float f) {
    unsigned int u = __float_as_uint(f);
    unsigned int r = u + 0x7FFFu + ((u >> 16) & 1u);
    return (unsigned short)(r >> 16);
}
__device__ inline float bf_lo(unsigned int u) { return __uint_as_float(u << 16); }
__device__ inline float bf_hi(unsigned int u) { return __uint_as_float(u & 0xFFFF0000u); }

// ---------------------------------------------------------------------------
// Fused prep.  Histogram FIRST (R14: its atomic-return stalls overlap with
// the streaming W-split blocks dispatched after).  X hi/lo split REMOVED:
// gemm1 now converts f32 X in-register (same bytes/lane, saves 41 MB traffic).
__global__ __launch_bounds__(256) void prep_kernel(const float* __restrict__ W1,
                                                   const float* __restrict__ W2,
                                                   unsigned short* __restrict__ Wt1Hi,
                                                   unsigned short* __restrict__ Wt1Lo,
                                                   unsigned short* __restrict__ Wt2Hi,
                                                   unsigned short* __restrict__ Wt2Lo,
                                                   int hb,
                                                   const int* __restrict__ col,
                                                   int* __restrict__ cnt,
                                                   int* __restrict__ rank, int E) {
    if (blockIdx.x < (unsigned)hb) {
        int e = blockIdx.x * 256 + threadIdx.x;
        if (e < E) rank[e] = atomicAdd(&cnt[col[e]], 1);
    } else {
        int i = (blockIdx.x - hb) * 256 + threadIdx.x;   // 0..32767
        const float* src   = (i < 16384) ? W1    : W2;
        unsigned short* dh = (i < 16384) ? Wt1Hi : Wt2Hi;
        unsigned short* dl = (i < 16384) ? Wt1Lo : Wt2Lo;
        int idx = i & 16383;
        int k = idx >> 7, n = idx & 127;
        float v = src[idx];                        // W[k][n]
        unsigned short hbv = f2bf_rne(v);
        float hf = __uint_as_float((unsigned int)hbv << 16);
        unsigned short lb = f2bf_rne(v - hf);
        dh[n * H_DIM + k] = hbv;
        dl[n * H_DIM + k] = lb;
    }
}

// ---------------------------------------------------------------------------
// Scan phase1: per-block reduce of cnt + dinv computation.
__global__ __launch_bounds__(256) void scan_phase1(const int* __restrict__ cnt,
                                                   int* __restrict__ blockSums,
                                                   float* __restrict__ dinv, int N) {
    __shared__ int red[256];
    int base = blockIdx.x * 1024;
    int t = threadIdx.x;
    int s = 0;
    for (int i = 0; i < 4; ++i) {
        int idx = base + t * 4 + i;
        if (idx < N) {
            int cv = cnt[idx];
            s += cv;
            dinv[idx] = rsqrtf((float)cv + 1.0f);   // deg>=1 (self loop)
        }
    }
    red[t] = s;
    __syncthreads();
    for (int d = 128; d > 0; d >>= 1) {
        if (t < d) red[t] += red[t + d];
        __syncthreads();
    }
    if (t == 0) blockSums[blockIdx.x] = red[0];
}

// ---------------------------------------------------------------------------
// Scan phase2+3 fused.
__global__ __launch_bounds__(256) void scan_phase23(const int* __restrict__ cnt,
                                                    const int* __restrict__ blockSums,
                                                    int* __restrict__ offs, int N, int B) {
    __shared__ int red[256];
    __shared__ int bsum[256];
    int base = blockIdx.x * 1024;
    int t = threadIdx.x;

    bsum[t] = (t < B && t < (int)blockIdx.x) ? blockSums[t] : 0;

    int v[4];
    int s = 0;
    for (int i = 0; i < 4; ++i) {
        int idx = base + t * 4 + i;
        v[i] = (idx < N) ? cnt[idx] : 0;
        s += v[i];
    }
    red[t] = s;
    __syncthreads();
    for (int d = 128; d > 0; d >>= 1) {
        if (t < d) bsum[t] += bsum[t + d];
        __syncthreads();
    }
    for (int d = 1; d < 256; d <<= 1) {
        int x = (t >= d) ? red[t - d] : 0;
        __syncthreads();
        red[t] += x;
        __syncthreads();
    }
    int run = bsum[0] + ((t == 0) ? 0 : red[t - 1]);
    for (int i = 0; i < 4; ++i) {
        int idx = base + t * 4 + i;
        if (idx < N) { offs[idx] = run; run += v[i]; }
    }
    if ((int)blockIdx.x == B - 1 && t == 255) offs[N] = run;   // == E
}

// ---------------------------------------------------------------------------
// FUSED scatter + layer-1 GEMM.  GEMM branch now reads f32 X directly and
// builds the hi/lo bf16 split in-register (bit-identical to the old staged
// path; same bytes/lane: 32 B f32 == 16 B hi + 16 B lo).
__global__ __launch_bounds__(256) void scatter_gemm1(
        const int* __restrict__ row, const int* __restrict__ col,
        const int* __restrict__ rank, const float* __restrict__ dinv,
        const int* __restrict__ offs, int2* __restrict__ csr, int E, int sb,
        const float* __restrict__ Xf,
        const unsigned short* __restrict__ WtHi, const unsigned short* __restrict__ WtLo,
        unsigned short* __restrict__ Yb, int N) {
    if (blockIdx.x < (unsigned)sb) {
        // ---- scatter branch: pos = offs[col] + rank, fire-and-forget store
        int e = blockIdx.x * 256 + threadIdx.x;
        if (e >= E) return;
        int r = row[e], c = col[e], rk = rank[e];
        int pos = offs[c] + rk;
        int2 p; p.x = r; p.y = __float_as_int(dinv[r] * dinv[c]);
        csr[pos] = p;
        return;
    }
    // ---- gemm branch
    int blk  = blockIdx.x - sb;
    int lane = threadIdx.x & 63;
    int wv   = threadIdx.x >> 6;
    int m16  = lane & 15;
    int quad = lane >> 4;
    int nodeBase = blk * 32;

    f32x4 acc[2][2] = {};

    #pragma unroll
    for (int kt = 0; kt < 4; ++kt) {
        int k0 = kt * 32 + quad * 8;

        ushort8 aHi[2], aLo[2];
        #pragma unroll
        for (int mi = 0; mi < 2; ++mi) {
            int node = nodeBase + mi * 16 + m16;
            if (node >= N) node = N - 1;
            const float* p = Xf + (size_t)node * H_DIM + k0;
            f32x4 u = *(const f32x4*)p;
            f32x4 w = *(const f32x4*)(p + 4);
            float vv[8] = {u.x, u.y, u.z, u.w, w.x, w.y, w.z, w.w};
            #pragma unroll
            for (int j = 0; j < 8; ++j) {
                unsigned short hbv = f2bf_rne(vv[j]);
                aHi[mi][j] = hbv;
                aLo[mi][j] = f2bf_rne(vv[j] - __uint_as_float((unsigned int)hbv << 16));
            }
        }

        ushort8 bHi[2], bLo[2];
        #pragma unroll
        for (int ni = 0; ni < 2; ++ni) {
            int n = (wv * 2 + ni) * 16 + m16;
            size_t off = (size_t)n * H_DIM + k0;
            bHi[ni] = *(const ushort8*)(WtHi + off);
            bLo[ni] = *(const ushort8*)(WtLo + off);
        }

        #pragma unroll
        for (int mi = 0; mi < 2; ++mi)
            #pragma unroll
            for (int ni = 0; ni < 2; ++ni) {
                acc[mi][ni] = __builtin_amdgcn_mfma_f32_16x16x32_bf16(
                    __builtin_bit_cast(bf16x8, aHi[mi]),
                    __builtin_bit_cast(bf16x8, bHi[ni]), acc[mi][ni], 0, 0, 0);
                acc[mi][ni] = __builtin_amdgcn_mfma_f32_16x16x32_bf16(
                    __builtin_bit_cast(bf16x8, aLo[mi]),
                    __builtin_bit_cast(bf16x8, bHi[ni]), acc[mi][ni], 0, 0, 0);
                acc[mi][ni] = __builtin_amdgcn_mfma_f32_16x16x32_bf16(
                    __builtin_bit_cast(bf16x8, aHi[mi]),
                    __builtin_bit_cast(bf16x8, bLo[ni]), acc[mi][ni], 0, 0, 0);
            }
    }

    #pragma unroll
    for (int mi = 0; mi < 2; ++mi)
        #pragma unroll
        for (int r = 0; r < 4; ++r) {
            int node = nodeBase + mi * 16 + quad * 4 + r;
            if (node < N) {
                #pragma unroll
                for (int ni = 0; ni < 2; ++ni) {
                    int c = (wv * 2 + ni) * 16 + m16;
                    Yb[(size_t)node * H_DIM + c] = f2bf_rne(acc[mi][ni][r]);
                }
            }
        }
}

// ---------------------------------------------------------------------------
// Layer-2 GEMM: bf16 A (exact, 16B loads, 2 MFMAs) -> bf16 out.
__global__ __launch_bounds__(256) void gemm_mfma_bf16A(const unsigned short* __restrict__ Xb,
                                                       const unsigned short* __restrict__ WtHi,
                                                       const unsigned short* __restrict__ WtLo,
                                                       unsigned short* __restrict__ Yb, int N) {
    int lane = threadIdx.x & 63;
    int wv   = threadIdx.x >> 6;
    int m16  = lane & 15;
    int quad = lane >> 4;
    int nodeBase = blockIdx.x * 32;

    f32x4 acc[2][2] = {};

    #pragma unroll
    for (int kt = 0; kt < 4; ++kt) {
        int k0 = kt * 32 + quad * 8;

        ushort8 a[2];
        #pragma unroll
        for (int mi = 0; mi < 2; ++mi) {
            int node = nodeBase + mi * 16 + m16;
            if (node >= N) node = N - 1;
            a[mi] = *(const ushort8*)(Xb + (size_t)node * H_DIM + k0);
        }

        ushort8 bHi[2], bLo[2];
        #pragma unroll
        for (int ni = 0; ni < 2; ++ni) {
            int n = (wv * 2 + ni) * 16 + m16;
            size_t off = (size_t)n * H_DIM + k0;
            bHi[ni] = *(const ushort8*)(WtHi + off);
            bLo[ni] = *(const ushort8*)(WtLo + off);
        }

        #pragma unroll
        for (int mi = 0; mi < 2; ++mi)
            #pragma unroll
            for (int ni = 0; ni < 2; ++ni) {
                acc[mi][ni] = __builtin_amdgcn_mfma_f32_16x16x32_bf16(
                    __builtin_bit_cast(bf16x8, a[mi]),
                    __builtin_bit_cast(bf16x8, bHi[ni]), acc[mi][ni], 0, 0, 0);
                acc[mi][ni] = __builtin_amdgcn_mfma_f32_16x16x32_bf16(
                    __builtin_bit_cast(bf16x8, a[mi]),
                    __builtin_bit_cast(bf16x8, bLo[ni]), acc[mi][ni], 0, 0, 0);
            }
    }

    #pragma unroll
    for (int mi = 0; mi < 2; ++mi)
        #pragma unroll
        for (int r = 0; r < 4; ++r) {
            int node = nodeBase + mi * 16 + quad * 4 + r;
            if (node < N) {
                #pragma unroll
                for (int ni = 0; ni < 2; ++ni) {
                    int c = (wv * 2 + ni) * 16 + m16;
                    Yb[(size_t)node * H_DIM + c] = f2bf_rne(acc[mi][ni][r]);
                }
            }
        }
}

// ---------------------------------------------------------------------------
// One wave per destination node.  Cooperative csr staging + 4-deep gather
// pipeline.  LOW VGPR (~12) is the point: 8 waves/SIMD resident.
// POOL=0: write bf16 rows (layer 1, feeds gemm2).
// POOL=1: skip the Hb write entirely; run-accumulate the block's 4 nodes
//   in LDS (batch sorted => <=2 graph runs/block) and atomicAdd once per
//   (graph,feature) per block into pooledSum.  Saves 20 MB Hb round-trip
//   and the pool_partial dispatch.
template <int POOL>
__global__ __launch_bounds__(256) void agg_fused_t(const unsigned short* __restrict__ XWb,
                                                   const float* __restrict__ dinv,
                                                   const int2* __restrict__ csr,
                                                   const int* __restrict__ offs,
                                                   const float* __restrict__ bias,
                                                   unsigned short* __restrict__ OUTb,
                                                   const int* __restrict__ batch,
                                                   float* __restrict__ pooledSum, int N) {
    int wave = (blockIdx.x * 256 + threadIdx.x) >> 6;
    int lane = threadIdx.x & 63;
    int wv   = threadIdx.x >> 6;
    bool active = wave < N;
    if (!POOL && !active) return;

    float ax = 0.f, ay = 0.f;
    int c = wave;
    if (active) {
        int start = offs[c], end = offs[c + 1];
        float dc = dinv[c];
        const unsigned int* XW32 = (const unsigned int*)XWb;

        float ax0, ay0;
        {   // self loop
            unsigned int u = XW32[(size_t)c * 64 + lane];
            float s = dc * dc;
            ax0 = bf_lo(u) * s; ay0 = bf_hi(u) * s;
        }
        float ax1 = 0.f, ay1 = 0.f, ax2 = 0.f, ay2 = 0.f, ax3 = 0.f, ay3 = 0.f;

        for (int base = start; base < end; base += 64) {
            int m = end - base; if (m > 64) m = 64;
            int2 ce; ce.x = 0; ce.y = 0;
            if (lane < m) ce = csr[base + lane];          // coalesced segment stage

            int j = 0;
            for (; j + 3 < m; j += 4) {
                int r0 = __shfl(ce.x, j);     int b0 = __shfl(ce.y, j);
                int r1 = __shfl(ce.x, j + 1); int b1 = __shfl(ce.y, j + 1);
                int r2 = __shfl(ce.x, j + 2); int b2 = __shfl(ce.y, j + 2);
                int r3 = __shfl(ce.x, j + 3); int b3 = __shfl(ce.y, j + 3);
                unsigned int g0 = XW32[(size_t)r0 * 64 + lane];
                unsigned int g1 = XW32[(size_t)r1 * 64 + lane];
                unsigned int g2 = XW32[(size_t)r2 * 64 + lane];
                unsigned int g3 = XW32[(size_t)r3 * 64 + lane];
                float n0 = __int_as_float(b0);
                float n1 = __int_as_float(b1);
                float n2 = __int_as_float(b2);
                float n3 = __int_as_float(b3);
                ax0 += bf_lo(g0) * n0; ay0 += bf_hi(g0) * n0;
                ax1 += bf_lo(g1) * n1; ay1 += bf_hi(g1) * n1;
                ax2 += bf_lo(g2) * n2; ay2 += bf_hi(g2) * n2;
                ax3 += bf_lo(g3) * n3; ay3 += bf_hi(g3) * n3;
            }
            for (; j < m; ++j) {
                int r = __shfl(ce.x, j); int b = __shfl(ce.y, j);
                unsigned int g = XW32[(size_t)r * 64 + lane];
                float nrm = __int_as_float(b);
                ax1 += bf_lo(g) * nrm; ay1 += bf_hi(g) * nrm;
            }
        }
        ax = (ax0 + ax1) + (ax2 + ax3);
        ay = (ay0 + ay1) + (ay2 + ay3);
        float2 b = ((const float2*)bias)[lane];
        ax = fmaxf(ax + b.x, 0.f);
        ay = fmaxf(ay + b.y, 0.f);
    }

    if constexpr (!POOL) {
        unsigned int o = (unsigned int)f2bf_rne(ax) | ((unsigned int)f2bf_rne(ay) << 16);
        ((unsigned int*)(OUTb + (size_t)c * H_DIM))[lane] = o;
        return;
    } else {
        __shared__ float lacc[4][H_DIM];
        __shared__ int lg[4];
        if (lane == 0) lg[wv] = active ? batch[c] : -1;
        float2 t2; t2.x = ax; t2.y = ay;
        ((float2*)(&lacc[wv][0]))[lane] = t2;             // b64, conflict-free
        __syncthreads();
        int t = threadIdx.x;
        if (t < H_DIM) {
            float s = 0.f; int cur = -1;
            #pragma unroll
            for (int w = 0; w < 4; ++w) {
                int g = lg[w];
                if (g < 0) continue;
                if (g != cur) {
                    if (cur >= 0) atomicAdd(&pooledSum[cur * H_DIM + t], s);
                    s = 0.f; cur = g;
                }
                s += lacc[w][t];
            }
            if (cur >= 0) atomicAdd(&pooledSum[cur * H_DIM + t], s);
        }
    }
}

// ---------------------------------------------------------------------------
// Head: count via binary search on sorted batch, mean, FC, log-softmax.
__global__ __launch_bounds__(64) void head_kernel(const float* __restrict__ pooledSum,
                                                  const int* __restrict__ batch,
                                                  const float* __restrict__ Wfc,
                                                  const float* __restrict__ bfc,
                                                  float* __restrict__ out, int N) {
    __shared__ float sl[OUT_DIM + 2];
    __shared__ int bounds[2];
    int g = blockIdx.x;
    int j = threadIdx.x;
    if (j < 2) {
        int v = g + j;
        int lo = 0, hi = N;
        while (lo < hi) {
            int mid = (lo + hi) >> 1;
            if (batch[mid] < v) lo = mid + 1; else hi = mid;
        }
        bounds[j] = lo;
    }
    __syncthreads();
    int cnt = bounds[1] - bounds[0];
    float inv = 1.0f / (float)(cnt > 0 ? cnt : 1);
    if (j < OUT_DIM) {
        float acc = 0.f;
        const float* p = pooledSum + g * H_DIM;
        for (int k = 0; k < H_DIM; ++k) acc += p[k] * Wfc[k * OUT_DIM + j];
        sl[j] = acc * inv + bfc[j];
    }
    __syncthreads();
    if (j == 0) {
        float m = sl[0];
        for (int i = 1; i < OUT_DIM; ++i) m = fmaxf(m, sl[i]);
        float s = 0.f;
        for (int i = 0; i < OUT_DIM; ++i) s += expf(sl[i] - m);
        sl[OUT_DIM] = m + logf(s);
    }
    __syncthreads();
    if (j < OUT_DIM) out[g * OUT_DIM + j] = sl[j] - sl[OUT_DIM];
}

// ---------------------------------------------------------------------------
extern "C" void kernel_launch(void* const* d_in, const int* in_sizes, int n_in,
                              void* d_out, int out_size, void* d_ws, size_t ws_size,
                              hipStream_t stream) {
    const float* x     = (const float*)d_in[0];
    const int*   ei    = (const int*)  d_in[1];
    const int*   batch = (const int*)  d_in[2];
    const float* W1    = (const float*)d_in[3];
    const float* b1    = (const float*)d_in[4];
    const float* W2    = (const float*)d_in[5];
    const float* b2    = (const float*)d_in[6];
    const float* Wfc   = (const float*)d_in[7];
    const float* bfc   = (const float*)d_in[8];
    float* out = (float*)d_out;

    int N = in_sizes[2];
    int E = in_sizes[1] / 2;
    int G = out_size / OUT_DIM;
    const int* row = ei;
    const int* col = ei + E;

    // Workspace layout (ONE memset zeroes cnt+pooledSum, adjacent):
    // cnt[nAlign] | pooledSum[G*128] | offs[nAlign] | rank[E] | dinv[nAlign]
    //   | csr[E] int2 | Xb[N*128] us | Hb[N*128] us
    //   | blockSums[256] | Wt{1,2}{Hi,Lo}[16384] us
    char* wsb = (char*)d_ws;
    size_t nAlign = (size_t)((N + 256) / 256) * 256;   // >= N+1
    size_t eAlign = (size_t)((E + 255) / 256) * 256;
    int*   cnt       = (int*)wsb;
    float* pooledSum = (float*)(cnt + nAlign);
    int*   offs      = (int*)(pooledSum + (size_t)G * H_DIM);
    int*   rank      = offs + nAlign;
    float* dinv      = (float*)(rank + eAlign);
    int2*  csr       = (int2*)(dinv + nAlign);
    unsigned short* Xb = (unsigned short*)(csr + E);
    unsigned short* Hb = Xb + (size_t)N * H_DIM;
    int* blockSums = (int*)(Hb + (size_t)N * H_DIM);
    unsigned short* Wt1Hi = (unsigned short*)(blockSums + 256);
    unsigned short* Wt1Lo = Wt1Hi + H_DIM * H_DIM;
    unsigned short* Wt2Hi = Wt1Lo + H_DIM * H_DIM;
    unsigned short* Wt2Lo = Wt2Hi + H_DIM * H_DIM;

    int scanBlocks = (N + 1023) / 1024;   // 40 for N=40000 (<=256 supported)
    int histBlocks = (E + 255) / 256;
    int gemmBlocks = (N + 31) / 32;       // 32 nodes/block

    // ---- One memset for cnt + pooledSum (adjacent)
    hipMemsetAsync(cnt, 0, (nAlign + (size_t)G * H_DIM) * sizeof(int), stream);

    // ---- Fused histogram (FIRST) + W-split (X-split eliminated)
    prep_kernel<<<histBlocks + 128, 256, 0, stream>>>(
        W1, W2, Wt1Hi, Wt1Lo, Wt2Hi, Wt2Lo, histBlocks, col, cnt, rank, E);

    // ---- 2-dispatch scan (phase2 folded into phase3)
    scan_phase1<<<scanBlocks, 256, 0, stream>>>(cnt, blockSums, dinv, N);
    scan_phase23<<<scanBlocks, 256, 0, stream>>>(cnt, blockSums, offs, N, scanBlocks);

    // ---- FUSED scatter + layer-1 GEMM (f32 X read + in-register hi/lo split)
    scatter_gemm1<<<histBlocks + gemmBlocks, 256, 0, stream>>>(
        row, col, rank, dinv, offs, csr, E, histBlocks,
        x, Wt1Hi, Wt1Lo, Xb, N);

    int aggBlocks = (N + 3) / 4;          // 4 waves/block, 1 wave/node

    // ---- Layer 1 aggregation -> Hb (bf16)
    agg_fused_t<0><<<aggBlocks, 256, 0, stream>>>(Xb, dinv, csr, offs, b1, Hb,
                                                  nullptr, nullptr, N);

    // ---- Layer 2 GEMM (reuse Xb for XW2)
    gemm_mfma_bf16A<<<gemmBlocks, 256, 0, stream>>>(Hb, Wt2Hi, Wt2Lo, Xb, N);

    // ---- Layer 2 aggregation + FUSED pooling (no Hb write, no pool dispatch)
    agg_fused_t<1><<<aggBlocks, 256, 0, stream>>>(Xb, dinv, csr, offs, b2, nullptr,
                                                  batch, pooledSum, N);

    // ---- Head (count/divide folded in)
    head_kernel<<<G, 64, 0, stream>>>(pooledSum, batch, Wfc, bfc, out, N);
}

// Round 2
// 227.435 us; speedup vs baseline: 1.0957x; 1.0126x over previous
//
#include <hip/hip_runtime.h>
#include <math.h>

#define H_DIM 128
#define OUT_DIM 10

typedef __attribute__((ext_vector_type(8))) __bf16 bf16x8;
typedef __attribute__((ext_vector_type(8))) unsigned short ushort8;
typedef __attribute__((ext_vector_type(4))) float f32x4;

__device__ inline unsigned short f2bf_rne(float f) {
    unsigned int u = __float_as_uint(f);
    unsigned int r = u + 0x7FFFu + ((u >> 16) & 1u);
    return (unsigned short)(r >> 16);
}
__device__ inline float bf_lo(unsigned int u) { return __uint_as_float(u << 16); }
__device__ inline float bf_hi(unsigned int u) { return __uint_as_float(u & 0xFFFF0000u); }

// ---------------------------------------------------------------------------
// Fused prep.  Histogram FIRST (atomic-return stalls overlap with the
// streaming W-split blocks dispatched after).
__global__ __launch_bounds__(256) void prep_kernel(const float* __restrict__ W1,
                                                   const float* __restrict__ W2,
                                                   unsigned short* __restrict__ Wt1Hi,
                                                   unsigned short* __restrict__ Wt1Lo,
                                                   unsigned short* __restrict__ Wt2Hi,
                                                   unsigned short* __restrict__ Wt2Lo,
                                                   int hb,
                                                   const int* __restrict__ col,
                                                   int* __restrict__ cnt,
                                                   int* __restrict__ rank, int E) {
    if (blockIdx.x < (unsigned)hb) {
        int e = blockIdx.x * 256 + threadIdx.x;
        if (e < E) rank[e] = atomicAdd(&cnt[col[e]], 1);
    } else {
        int i = (blockIdx.x - hb) * 256 + threadIdx.x;   // 0..32767
        const float* src   = (i < 16384) ? W1    : W2;
        unsigned short* dh = (i < 16384) ? Wt1Hi : Wt2Hi;
        unsigned short* dl = (i < 16384) ? Wt1Lo : Wt2Lo;
        int idx = i & 16383;
        int k = idx >> 7, n = idx & 127;
        float v = src[idx];                        // W[k][n]
        unsigned short hbv = f2bf_rne(v);
        float hf = __uint_as_float((unsigned int)hbv << 16);
        unsigned short lb = f2bf_rne(v - hf);
        dh[n * H_DIM + k] = hbv;
        dl[n * H_DIM + k] = lb;
    }
}

// ---------------------------------------------------------------------------
// Scan phase1: per-block reduce of cnt + dinv computation.
__global__ __launch_bounds__(256) void scan_phase1(const int* __restrict__ cnt,
                                                   int* __restrict__ blockSums,
                                                   float* __restrict__ dinv, int N) {
    __shared__ int red[256];
    int base = blockIdx.x * 1024;
    int t = threadIdx.x;
    int s = 0;
    for (int i = 0; i < 4; ++i) {
        int idx = base + t * 4 + i;
        if (idx < N) {
            int cv = cnt[idx];
            s += cv;
            dinv[idx] = rsqrtf((float)cv + 1.0f);   // deg>=1 (self loop)
        }
    }
    red[t] = s;
    __syncthreads();
    for (int d = 128; d > 0; d >>= 1) {
        if (t < d) red[t] += red[t + d];
        __syncthreads();
    }
    if (t == 0) blockSums[blockIdx.x] = red[0];
}

// ---------------------------------------------------------------------------
// Scan phase2+3 fused.
__global__ __launch_bounds__(256) void scan_phase23(const int* __restrict__ cnt,
                                                    const int* __restrict__ blockSums,
                                                    int* __restrict__ offs, int N, int B) {
    __shared__ int red[256];
    __shared__ int bsum[256];
    int base = blockIdx.x * 1024;
    int t = threadIdx.x;

    bsum[t] = (t < B && t < (int)blockIdx.x) ? blockSums[t] : 0;

    int v[4];
    int s = 0;
    for (int i = 0; i < 4; ++i) {
        int idx = base + t * 4 + i;
        v[i] = (idx < N) ? cnt[idx] : 0;
        s += v[i];
    }
    red[t] = s;
    __syncthreads();
    for (int d = 128; d > 0; d >>= 1) {
        if (t < d) bsum[t] += bsum[t + d];
        __syncthreads();
    }
    for (int d = 1; d < 256; d <<= 1) {
        int x = (t >= d) ? red[t - d] : 0;
        __syncthreads();
        red[t] += x;
        __syncthreads();
    }
    int run = bsum[0] + ((t == 0) ? 0 : red[t - 1]);
    for (int i = 0; i < 4; ++i) {
        int idx = base + t * 4 + i;
        if (idx < N) { offs[idx] = run; run += v[i]; }
    }
    if ((int)blockIdx.x == B - 1 && t == 255) offs[N] = run;   // == E
}

// ---------------------------------------------------------------------------
// FUSED scatter + layer-1 GEMM (f32 X read + in-register hi/lo split).
__global__ __launch_bounds__(256) void scatter_gemm1(
        const int* __restrict__ row, const int* __restrict__ col,
        const int* __restrict__ rank, const float* __restrict__ dinv,
        const int* __restrict__ offs, int2* __restrict__ csr, int E, int sb,
        const float* __restrict__ Xf,
        const unsigned short* __restrict__ WtHi, const unsigned short* __restrict__ WtLo,
        unsigned short* __restrict__ Yb, int N) {
    if (blockIdx.x < (unsigned)sb) {
        int e = blockIdx.x * 256 + threadIdx.x;
        if (e >= E) return;
        int r = row[e], c = col[e], rk = rank[e];
        int pos = offs[c] + rk;
        int2 p; p.x = r; p.y = __float_as_int(dinv[r] * dinv[c]);
        csr[pos] = p;
        return;
    }
    int blk  = blockIdx.x - sb;
    int lane = threadIdx.x & 63;
    int wv   = threadIdx.x >> 6;
    int m16  = lane & 15;
    int quad = lane >> 4;
    int nodeBase = blk * 32;

    f32x4 acc[2][2] = {};

    #pragma unroll
    for (int kt = 0; kt < 4; ++kt) {
        int k0 = kt * 32 + quad * 8;

        ushort8 aHi[2], aLo[2];
        #pragma unroll
        for (int mi = 0; mi < 2; ++mi) {
            int node = nodeBase + mi * 16 + m16;
            if (node >= N) node = N - 1;
            const float* p = Xf + (size_t)node * H_DIM + k0;
            f32x4 u = *(const f32x4*)p;
            f32x4 w = *(const f32x4*)(p + 4);
            float vv[8] = {u.x, u.y, u.z, u.w, w.x, w.y, w.z, w.w};
            #pragma unroll
            for (int j = 0; j < 8; ++j) {
                unsigned short hbv = f2bf_rne(vv[j]);
                aHi[mi][j] = hbv;
                aLo[mi][j] = f2bf_rne(vv[j] - __uint_as_float((unsigned int)hbv << 16));
            }
        }

        ushort8 bHi[2], bLo[2];
        #pragma unroll
        for (int ni = 0; ni < 2; ++ni) {
            int n = (wv * 2 + ni) * 16 + m16;
            size_t off = (size_t)n * H_DIM + k0;
            bHi[ni] = *(const ushort8*)(WtHi + off);
            bLo[ni] = *(const ushort8*)(WtLo + off);
        }

        #pragma unroll
        for (int mi = 0; mi < 2; ++mi)
            #pragma unroll
            for (int ni = 0; ni < 2; ++ni) {
                acc[mi][ni] = __builtin_amdgcn_mfma_f32_16x16x32_bf16(
                    __builtin_bit_cast(bf16x8, aHi[mi]),
                    __builtin_bit_cast(bf16x8, bHi[ni]), acc[mi][ni], 0, 0, 0);
                acc[mi][ni] = __builtin_amdgcn_mfma_f32_16x16x32_bf16(
                    __builtin_bit_cast(bf16x8, aLo[mi]),
                    __builtin_bit_cast(bf16x8, bHi[ni]), acc[mi][ni], 0, 0, 0);
                acc[mi][ni] = __builtin_amdgcn_mfma_f32_16x16x32_bf16(
                    __builtin_bit_cast(bf16x8, aHi[mi]),
                    __builtin_bit_cast(bf16x8, bLo[ni]), acc[mi][ni], 0, 0, 0);
            }
    }

    #pragma unroll
    for (int mi = 0; mi < 2; ++mi)
        #pragma unroll
        for (int r = 0; r < 4; ++r) {
            int node = nodeBase + mi * 16 + quad * 4 + r;
            if (node < N) {
                #pragma unroll
                for (int ni = 0; ni < 2; ++ni) {
                    int c = (wv * 2 + ni) * 16 + m16;
                    Yb[(size_t)node * H_DIM + c] = f2bf_rne(acc[mi][ni][r]);
                }
            }
        }
}

// ---------------------------------------------------------------------------
// FUSED layer-1 aggregation + layer-2 GEMM.
// Each block: 4 waves x 4 nodes = 16 h-rows.  Gather phase identical to the
// old agg (8-deep pipeline now), h rounded to bf16 (bit-identical to the old
// Hb path) and staged in LDS (+8-short pad -> conflict-free b128 reads).
// Then one 16x128 @ 128x128 MFMA GEMM per block writes XW2 directly,
// eliminating the Hb round-trip (20.5 MB) and the gemm2 dispatch.
__global__ __launch_bounds__(256) void agg1_gemm2(
        const unsigned short* __restrict__ XWb,
        const float* __restrict__ dinv,
        const int2* __restrict__ csr,
        const int* __restrict__ offs,
        const float* __restrict__ bias,
        const unsigned short* __restrict__ WtHi,   // W2 hi (transposed)
        const unsigned short* __restrict__ WtLo,   // W2 lo
        unsigned short* __restrict__ Yb,           // XW2 out
        int N) {
    __shared__ unsigned short hrow[16][136];       // +8 pad: conflict-free
    int lane = threadIdx.x & 63;
    int wv   = threadIdx.x >> 6;
    int nodeBase = blockIdx.x * 16;
    const unsigned int* XW32 = (const unsigned int*)XWb;
    float2 bv = ((const float2*)bias)[lane];

    for (int i = 0; i < 4; ++i) {
        int c = nodeBase + wv * 4 + i;
        float ax = 0.f, ay = 0.f;
        if (c < N) {
            int start = offs[c], end = offs[c + 1];
            float dc = dinv[c];
            float ax0, ay0;
            {   // self loop
                unsigned int u = XW32[(size_t)c * 64 + lane];
                float s = dc * dc;
                ax0 = bf_lo(u) * s; ay0 = bf_hi(u) * s;
            }
            float ax1 = 0.f, ay1 = 0.f, ax2 = 0.f, ay2 = 0.f, ax3 = 0.f, ay3 = 0.f;

            for (int base = start; base < end; base += 64) {
                int m = end - base; if (m > 64) m = 64;
                int2 ce; ce.x = 0; ce.y = 0;
                if (lane < m) ce = csr[base + lane];

                int j = 0;
                for (; j + 7 < m; j += 8) {
                    int r0 = __shfl(ce.x, j);     int b0 = __shfl(ce.y, j);
                    int r1 = __shfl(ce.x, j + 1); int b1 = __shfl(ce.y, j + 1);
                    int r2 = __shfl(ce.x, j + 2); int b2 = __shfl(ce.y, j + 2);
                    int r3 = __shfl(ce.x, j + 3); int b3 = __shfl(ce.y, j + 3);
                    int r4 = __shfl(ce.x, j + 4); int b4 = __shfl(ce.y, j + 4);
                    int r5 = __shfl(ce.x, j + 5); int b5 = __shfl(ce.y, j + 5);
                    int r6 = __shfl(ce.x, j + 6); int b6 = __shfl(ce.y, j + 6);
                    int r7 = __shfl(ce.x, j + 7); int b7 = __shfl(ce.y, j + 7);
                    unsigned int g0 = XW32[(size_t)r0 * 64 + lane];
                    unsigned int g1 = XW32[(size_t)r1 * 64 + lane];
                    unsigned int g2 = XW32[(size_t)r2 * 64 + lane];
                    unsigned int g3 = XW32[(size_t)r3 * 64 + lane];
                    unsigned int g4 = XW32[(size_t)r4 * 64 + lane];
                    unsigned int g5 = XW32[(size_t)r5 * 64 + lane];
                    unsigned int g6 = XW32[(size_t)r6 * 64 + lane];
                    unsigned int g7 = XW32[(size_t)r7 * 64 + lane];
                    ax0 += bf_lo(g0) * __int_as_float(b0); ay0 += bf_hi(g0) * __int_as_float(b0);
                    ax1 += bf_lo(g1) * __int_as_float(b1); ay1 += bf_hi(g1) * __int_as_float(b1);
                    ax2 += bf_lo(g2) * __int_as_float(b2); ay2 += bf_hi(g2) * __int_as_float(b2);
                    ax3 += bf_lo(g3) * __int_as_float(b3); ay3 += bf_hi(g3) * __int_as_float(b3);
                    ax0 += bf_lo(g4) * __int_as_float(b4); ay0 += bf_hi(g4) * __int_as_float(b4);
                    ax1 += bf_lo(g5) * __int_as_float(b5); ay1 += bf_hi(g5) * __int_as_float(b5);
                    ax2 += bf_lo(g6) * __int_as_float(b6); ay2 += bf_hi(g6) * __int_as_float(b6);
                    ax3 += bf_lo(g7) * __int_as_float(b7); ay3 += bf_hi(g7) * __int_as_float(b7);
                }
                for (; j + 3 < m; j += 4) {
                    int r0 = __shfl(ce.x, j);     int b0 = __shfl(ce.y, j);
                    int r1 = __shfl(ce.x, j + 1); int b1 = __shfl(ce.y, j + 1);
                    int r2 = __shfl(ce.x, j + 2); int b2 = __shfl(ce.y, j + 2);
                    int r3 = __shfl(ce.x, j + 3); int b3 = __shfl(ce.y, j + 3);
                    unsigned int g0 = XW32[(size_t)r0 * 64 + lane];
                    unsigned int g1 = XW32[(size_t)r1 * 64 + lane];
                    unsigned int g2 = XW32[(size_t)r2 * 64 + lane];
                    unsigned int g3 = XW32[(size_t)r3 * 64 + lane];
                    ax0 += bf_lo(g0) * __int_as_float(b0); ay0 += bf_hi(g0) * __int_as_float(b0);
                    ax1 += bf_lo(g1) * __int_as_float(b1); ay1 += bf_hi(g1) * __int_as_float(b1);
                    ax2 += bf_lo(g2) * __int_as_float(b2); ay2 += bf_hi(g2) * __int_as_float(b2);
                    ax3 += bf_lo(g3) * __int_as_float(b3); ay3 += bf_hi(g3) * __int_as_float(b3);
                }
                for (; j < m; ++j) {
                    int r = __shfl(ce.x, j); int b = __shfl(ce.y, j);
                    unsigned int g = XW32[(size_t)r * 64 + lane];
                    float nrm = __int_as_float(b);
                    ax1 += bf_lo(g) * nrm; ay1 += bf_hi(g) * nrm;
                }
            }
            ax = (ax0 + ax1) + (ax2 + ax3);
            ay = (ay0 + ay1) + (ay2 + ay3);
            ax = fmaxf(ax + bv.x, 0.f);
            ay = fmaxf(ay + bv.y, 0.f);
        }
        // stage h-row (same f2bf_rne rounding as the old Hb write)
        unsigned int o = (unsigned int)f2bf_rne(ax) | ((unsigned int)f2bf_rne(ay) << 16);
        *(unsigned int*)&hrow[wv * 4 + i][lane * 2] = o;
    }
    __syncthreads();

    // ---- layer-2 GEMM: hrow[16][128] @ W2[128][128]
    int m16  = lane & 15;
    int quad = lane >> 4;
    f32x4 acc[2] = {};
    #pragma unroll
    for (int kt = 0; kt < 4; ++kt) {
        int k0 = kt * 32 + quad * 8;
        ushort8 a = *(const ushort8*)&hrow[m16][k0];
        #pragma unroll
        for (int ni = 0; ni < 2; ++ni) {
            int n = (wv * 2 + ni) * 16 + m16;
            size_t off = (size_t)n * H_DIM + k0;
            ushort8 bHi = *(const ushort8*)(WtHi + off);
            ushort8 bLo = *(const ushort8*)(WtLo + off);
            acc[ni] = __builtin_amdgcn_mfma_f32_16x16x32_bf16(
                __builtin_bit_cast(bf16x8, a),
                __builtin_bit_cast(bf16x8, bHi), acc[ni], 0, 0, 0);
            acc[ni] = __builtin_amdgcn_mfma_f32_16x16x32_bf16(
                __builtin_bit_cast(bf16x8, a),
                __builtin_bit_cast(bf16x8, bLo), acc[ni], 0, 0, 0);
        }
    }
    #pragma unroll
    for (int r = 0; r < 4; ++r) {
        int node = nodeBase + quad * 4 + r;
        if (node < N) {
            #pragma unroll
            for (int ni = 0; ni < 2; ++ni) {
                int cc = (wv * 2 + ni) * 16 + m16;
                Yb[(size_t)node * H_DIM + cc] = f2bf_rne(acc[ni][r]);
            }
        }
    }
}

// ---------------------------------------------------------------------------
// Layer-2 aggregation + fused pooling.  One wave per node, 8-deep pipeline.
__global__ __launch_bounds__(256) void agg_pool(const unsigned short* __restrict__ XWb,
                                                const float* __restrict__ dinv,
                                                const int2* __restrict__ csr,
                                                const int* __restrict__ offs,
                                                const float* __restrict__ bias,
                                                const int* __restrict__ batch,
                                                float* __restrict__ pooledSum, int N) {
    int wave = (blockIdx.x * 256 + threadIdx.x) >> 6;
    int lane = threadIdx.x & 63;
    int wv   = threadIdx.x >> 6;
    bool active = wave < N;

    float ax = 0.f, ay = 0.f;
    int c = wave;
    if (active) {
        int start = offs[c], end = offs[c + 1];
        float dc = dinv[c];
        const unsigned int* XW32 = (const unsigned int*)XWb;

        float ax0, ay0;
        {   // self loop
            unsigned int u = XW32[(size_t)c * 64 + lane];
            float s = dc * dc;
            ax0 = bf_lo(u) * s; ay0 = bf_hi(u) * s;
        }
        float ax1 = 0.f, ay1 = 0.f, ax2 = 0.f, ay2 = 0.f, ax3 = 0.f, ay3 = 0.f;

        for (int base = start; base < end; base += 64) {
            int m = end - base; if (m > 64) m = 64;
            int2 ce; ce.x = 0; ce.y = 0;
            if (lane < m) ce = csr[base + lane];

            int j = 0;
            for (; j + 7 < m; j += 8) {
                int r0 = __shfl(ce.x, j);     int b0 = __shfl(ce.y, j);
                int r1 = __shfl(ce.x, j + 1); int b1 = __shfl(ce.y, j + 1);
                int r2 = __shfl(ce.x, j + 2); int b2 = __shfl(ce.y, j + 2);
                int r3 = __shfl(ce.x, j + 3); int b3 = __shfl(ce.y, j + 3);
                int r4 = __shfl(ce.x, j + 4); int b4 = __shfl(ce.y, j + 4);
                int r5 = __shfl(ce.x, j + 5); int b5 = __shfl(ce.y, j + 5);
                int r6 = __shfl(ce.x, j + 6); int b6 = __shfl(ce.y, j + 6);
                int r7 = __shfl(ce.x, j + 7); int b7 = __shfl(ce.y, j + 7);
                unsigned int g0 = XW32[(size_t)r0 * 64 + lane];
                unsigned int g1 = XW32[(size_t)r1 * 64 + lane];
                unsigned int g2 = XW32[(size_t)r2 * 64 + lane];
                unsigned int g3 = XW32[(size_t)r3 * 64 + lane];
                unsigned int g4 = XW32[(size_t)r4 * 64 + lane];
                unsigned int g5 = XW32[(size_t)r5 * 64 + lane];
                unsigned int g6 = XW32[(size_t)r6 * 64 + lane];
                unsigned int g7 = XW32[(size_t)r7 * 64 + lane];
                ax0 += bf_lo(g0) * __int_as_float(b0); ay0 += bf_hi(g0) * __int_as_float(b0);
                ax1 += bf_lo(g1) * __int_as_float(b1); ay1 += bf_hi(g1) * __int_as_float(b1);
                ax2 += bf_lo(g2) * __int_as_float(b2); ay2 += bf_hi(g2) * __int_as_float(b2);
                ax3 += bf_lo(g3) * __int_as_float(b3); ay3 += bf_hi(g3) * __int_as_float(b3);
                ax0 += bf_lo(g4) * __int_as_float(b4); ay0 += bf_hi(g4) * __int_as_float(b4);
                ax1 += bf_lo(g5) * __int_as_float(b5); ay1 += bf_hi(g5) * __int_as_float(b5);
                ax2 += bf_lo(g6) * __int_as_float(b6); ay2 += bf_hi(g6) * __int_as_float(b6);
                ax3 += bf_lo(g7) * __int_as_float(b7); ay3 += bf_hi(g7) * __int_as_float(b7);
            }
            for (; j + 3 < m; j += 4) {
                int r0 = __shfl(ce.x, j);     int b0 = __shfl(ce.y, j);
                int r1 = __shfl(ce.x, j + 1); int b1 = __shfl(ce.y, j + 1);
                int r2 = __shfl(ce.x, j + 2); int b2 = __shfl(ce.y, j + 2);
                int r3 = __shfl(ce.x, j + 3); int b3 = __shfl(ce.y, j + 3);
                unsigned int g0 = XW32[(size_t)r0 * 64 + lane];
                unsigned int g1 = XW32[(size_t)r1 * 64 + lane];
                unsigned int g2 = XW32[(size_t)r2 * 64 + lane];
                unsigned int g3 = XW32[(size_t)r3 * 64 + lane];
                ax0 += bf_lo(g0) * __int_as_float(b0); ay0 += bf_hi(g0) * __int_as_float(b0);
                ax1 += bf_lo(g1) * __int_as_float(b1); ay1 += bf_hi(g1) * __int_as_float(b1);
                ax2 += bf_lo(g2) * __int_as_float(b2); ay2 += bf_hi(g2) * __int_as_float(b2);
                ax3 += bf_lo(g3) * __int_as_float(b3); ay3 += bf_hi(g3) * __int_as_float(b3);
            }
            for (; j < m; ++j) {
                int r = __shfl(ce.x, j); int b = __shfl(ce.y, j);
                unsigned int g = XW32[(size_t)r * 64 + lane];
                float nrm = __int_as_float(b);
                ax1 += bf_lo(g) * nrm; ay1 += bf_hi(g) * nrm;
            }
        }
        ax = (ax0 + ax1) + (ax2 + ax3);
        ay = (ay0 + ay1) + (ay2 + ay3);
        float2 b = ((const float2*)bias)[lane];
        ax = fmaxf(ax + b.x, 0.f);
        ay = fmaxf(ay + b.y, 0.f);
    }

    __shared__ float lacc[4][H_DIM];
    __shared__ int lg[4];
    if (lane == 0) lg[wv] = active ? batch[c] : -1;
    float2 t2; t2.x = ax; t2.y = ay;
    ((float2*)(&lacc[wv][0]))[lane] = t2;             // b64, conflict-free
    __syncthreads();
    int t = threadIdx.x;
    if (t < H_DIM) {
        float s = 0.f; int cur = -1;
        #pragma unroll
        for (int w = 0; w < 4; ++w) {
            int g = lg[w];
            if (g < 0) continue;
            if (g != cur) {
                if (cur >= 0) atomicAdd(&pooledSum[cur * H_DIM + t], s);
                s = 0.f; cur = g;
            }
            s += lacc[w][t];
        }
        if (cur >= 0) atomicAdd(&pooledSum[cur * H_DIM + t], s);
    }
}

// ---------------------------------------------------------------------------
// Head: count via binary search on sorted batch, mean, FC, log-softmax.
__global__ __launch_bounds__(64) void head_kernel(const float* __restrict__ pooledSum,
                                                  const int* __restrict__ batch,
                                                  const float* __restrict__ Wfc,
                                                  const float* __restrict__ bfc,
                                                  float* __restrict__ out, int N) {
    __shared__ float sl[OUT_DIM + 2];
    __shared__ int bounds[2];
    int g = blockIdx.x;
    int j = threadIdx.x;
    if (j < 2) {
        int v = g + j;
        int lo = 0, hi = N;
        while (lo < hi) {
            int mid = (lo + hi) >> 1;
            if (batch[mid] < v) lo = mid + 1; else hi = mid;
        }
        bounds[j] = lo;
    }
    __syncthreads();
    int cnt = bounds[1] - bounds[0];
    float inv = 1.0f / (float)(cnt > 0 ? cnt : 1);
    if (j < OUT_DIM) {
        float acc = 0.f;
        const float* p = pooledSum + g * H_DIM;
        for (int k = 0; k < H_DIM; ++k) acc += p[k] * Wfc[k * OUT_DIM + j];
        sl[j] = acc * inv + bfc[j];
    }
    __syncthreads();
    if (j == 0) {
        float m = sl[0];
        for (int i = 1; i < OUT_DIM; ++i) m = fmaxf(m, sl[i]);
        float s = 0.f;
        for (int i = 0; i < OUT_DIM; ++i) s += expf(sl[i] - m);
        sl[OUT_DIM] = m + logf(s);
    }
    __syncthreads();
    if (j < OUT_DIM) out[g * OUT_DIM + j] = sl[j] - sl[OUT_DIM];
}

// ---------------------------------------------------------------------------
extern "C" void kernel_launch(void* const* d_in, const int* in_sizes, int n_in,
                              void* d_out, int out_size, void* d_ws, size_t ws_size,
                              hipStream_t stream) {
    const float* x     = (const float*)d_in[0];
    const int*   ei    = (const int*)  d_in[1];
    const int*   batch = (const int*)  d_in[2];
    const float* W1    = (const float*)d_in[3];
    const float* b1    = (const float*)d_in[4];
    const float* W2    = (const float*)d_in[5];
    const float* b2    = (const float*)d_in[6];
    const float* Wfc   = (const float*)d_in[7];
    const float* bfc   = (const float*)d_in[8];
    float* out = (float*)d_out;

    int N = in_sizes[2];
    int E = in_sizes[1] / 2;
    int G = out_size / OUT_DIM;
    const int* row = ei;
    const int* col = ei + E;

    // Workspace layout (ONE memset zeroes cnt+pooledSum, adjacent):
    // cnt[nAlign] | pooledSum[G*128] | offs[nAlign] | rank[E] | dinv[nAlign]
    //   | csr[E] int2 | Xb[N*128] us | Hb[N*128] us
    //   | blockSums[256] | Wt{1,2}{Hi,Lo}[16384] us
    char* wsb = (char*)d_ws;
    size_t nAlign = (size_t)((N + 256) / 256) * 256;   // >= N+1
    size_t eAlign = (size_t)((E + 255) / 256) * 256;
    int*   cnt       = (int*)wsb;
    float* pooledSum = (float*)(cnt + nAlign);
    int*   offs      = (int*)(pooledSum + (size_t)G * H_DIM);
    int*   rank      = offs + nAlign;
    float* dinv      = (float*)(rank + eAlign);
    int2*  csr       = (int2*)(dinv + nAlign);
    unsigned short* Xb = (unsigned short*)(csr + E);
    unsigned short* Hb = Xb + (size_t)N * H_DIM;
    int* blockSums = (int*)(Hb + (size_t)N * H_DIM);
    unsigned short* Wt1Hi = (unsigned short*)(blockSums + 256);
    unsigned short* Wt1Lo = Wt1Hi + H_DIM * H_DIM;
    unsigned short* Wt2Hi = Wt1Lo + H_DIM * H_DIM;
    unsigned short* Wt2Lo = Wt2Hi + H_DIM * H_DIM;

    int scanBlocks = (N + 1023) / 1024;   // 40 for N=40000 (<=256 supported)
    int histBlocks = (E + 255) / 256;
    int gemmBlocks = (N + 31) / 32;       // 32 nodes/block (layer 1)

    // ---- One memset for cnt + pooledSum (adjacent)
    hipMemsetAsync(cnt, 0, (nAlign + (size_t)G * H_DIM) * sizeof(int), stream);

    // ---- Fused histogram (FIRST) + W-split
    prep_kernel<<<histBlocks + 128, 256, 0, stream>>>(
        W1, W2, Wt1Hi, Wt1Lo, Wt2Hi, Wt2Lo, histBlocks, col, cnt, rank, E);

    // ---- 2-dispatch scan
    scan_phase1<<<scanBlocks, 256, 0, stream>>>(cnt, blockSums, dinv, N);
    scan_phase23<<<scanBlocks, 256, 0, stream>>>(cnt, blockSums, offs, N, scanBlocks);

    // ---- FUSED scatter + layer-1 GEMM -> Xb
    scatter_gemm1<<<histBlocks + gemmBlocks, 256, 0, stream>>>(
        row, col, rank, dinv, offs, csr, E, histBlocks,
        x, Wt1Hi, Wt1Lo, Xb, N);

    // ---- FUSED layer-1 aggregation + layer-2 GEMM -> Hb (holds XW2 now)
    int ag1Blocks = (N + 15) / 16;        // 16 nodes/block
    agg1_gemm2<<<ag1Blocks, 256, 0, stream>>>(Xb, dinv, csr, offs, b1,
                                              Wt2Hi, Wt2Lo, Hb, N);

    // ---- Layer-2 aggregation + fused pooling
    int aggBlocks = (N + 3) / 4;          // 4 waves/block, 1 wave/node
    agg_pool<<<aggBlocks, 256, 0, stream>>>(Hb, dinv, csr, offs, b2,
                                            batch, pooledSum, N);

    // ---- Head (count/divide folded in)
    head_kernel<<<G, 64, 0, stream>>>(pooledSum, batch, Wfc, bfc, out, N);
}

// Round 4
// 222.303 us; speedup vs baseline: 1.1210x; 1.0231x over previous
//
#include <hip/hip_runtime.h>
#include <math.h>

#define H_DIM 128
#define OUT_DIM 10

typedef __attribute__((ext_vector_type(8))) __bf16 bf16x8;
typedef __attribute__((ext_vector_type(8))) unsigned short ushort8;
typedef __attribute__((ext_vector_type(4))) float f32x4;

__device__ inline unsigned short f2bf_rne(float f) {
    unsigned int u = __float_as_uint(f);
    unsigned int r = u + 0x7FFFu + ((u >> 16) & 1u);
    return (unsigned short)(r >> 16);
}
__device__ inline float bf_lo(unsigned int u) { return __uint_as_float(u << 16); }
__device__ inline float bf_hi(unsigned int u) { return __uint_as_float(u & 0xFFFF0000u); }

// Accumulate one 16B fragment (8 bf16 features) scaled by n into ax/ay[4].
#define ACC4(gv, nv) do { \
    const unsigned int* _u = (const unsigned int*)&(gv); \
    ax[0] += bf_lo(_u[0]) * (nv); ay[0] += bf_hi(_u[0]) * (nv); \
    ax[1] += bf_lo(_u[1]) * (nv); ay[1] += bf_hi(_u[1]) * (nv); \
    ax[2] += bf_lo(_u[2]) * (nv); ay[2] += bf_hi(_u[2]) * (nv); \
    ax[3] += bf_lo(_u[3]) * (nv); ay[3] += bf_hi(_u[3]) * (nv); \
} while (0)

// ---------------------------------------------------------------------------
// dwordx4 gather engine: 4 rows per load instruction.  Subgroup sub=lane>>4
// handles rows 4g+sub; fl=lane&15 owns features fl*8..fl*8+7 (16B).
// Tail rows padded with (idx=c, norm=0).  SELF-LOOP ONLY IN sub==0 (the
// butterfly sums subgroups — R3 bug was 4x self-loop).  Ends with a
// cross-subgroup butterfly so ALL lanes hold full sums for their fl.
__device__ inline void gather_node(const int4* __restrict__ XW16,
                                   const int2* __restrict__ csr,
                                   int start, int end, int c, float dc2,
                                   int sub, int fl, int lane,
                                   float ax[4], float ay[4]) {
    {   // self loop — counted once: zero scale in subgroups 1..3
        float s = (sub == 0) ? dc2 : 0.0f;
        int4 gs = XW16[(size_t)c * 16 + fl];
        const unsigned int* u = (const unsigned int*)&gs;
        ax[0] = bf_lo(u[0]) * s; ay[0] = bf_hi(u[0]) * s;
        ax[1] = bf_lo(u[1]) * s; ay[1] = bf_hi(u[1]) * s;
        ax[2] = bf_lo(u[2]) * s; ay[2] = bf_hi(u[2]) * s;
        ax[3] = bf_lo(u[3]) * s; ay[3] = bf_hi(u[3]) * s;
    }
    for (int base = start; base < end; base += 64) {
        int m = end - base; if (m > 64) m = 64;
        int2 ce; ce.x = c; ce.y = 0;                  // pad: valid idx, zero norm
        if (lane < m) ce = csr[base + lane];
        int groups = (m + 3) >> 2;
        int g = 0;
        for (; g + 3 < groups; g += 4) {              // 16 rows, 4 loads in flight
            int j = g * 4 + sub;
            int r0 = __shfl(ce.x, j);      float n0 = __int_as_float(__shfl(ce.y, j));
            int r1 = __shfl(ce.x, j + 4);  float n1 = __int_as_float(__shfl(ce.y, j + 4));
            int r2 = __shfl(ce.x, j + 8);  float n2 = __int_as_float(__shfl(ce.y, j + 8));
            int r3 = __shfl(ce.x, j + 12); float n3 = __int_as_float(__shfl(ce.y, j + 12));
            int4 g0 = XW16[(size_t)r0 * 16 + fl];
            int4 g1 = XW16[(size_t)r1 * 16 + fl];
            int4 g2 = XW16[(size_t)r2 * 16 + fl];
            int4 g3 = XW16[(size_t)r3 * 16 + fl];
            ACC4(g0, n0); ACC4(g1, n1); ACC4(g2, n2); ACC4(g3, n3);
        }
        for (; g < groups; ++g) {                     // 4 rows per iteration
            int j = g * 4 + sub;
            int r = __shfl(ce.x, j); float n = __int_as_float(__shfl(ce.y, j));
            int4 gg = XW16[(size_t)r * 16 + fl];
            ACC4(gg, n);
        }
    }
    #pragma unroll
    for (int q = 0; q < 4; ++q) {                     // cross-subgroup butterfly
        ax[q] += __shfl_xor(ax[q], 16); ax[q] += __shfl_xor(ax[q], 32);
        ay[q] += __shfl_xor(ay[q], 16); ay[q] += __shfl_xor(ay[q], 32);
    }
}

// ---------------------------------------------------------------------------
// Fused prep.  Histogram FIRST (atomic-return stalls overlap with the
// streaming W-split blocks dispatched after).
__global__ __launch_bounds__(256) void prep_kernel(const float* __restrict__ W1,
                                                   const float* __restrict__ W2,
                                                   unsigned short* __restrict__ Wt1Hi,
                                                   unsigned short* __restrict__ Wt1Lo,
                                                   unsigned short* __restrict__ Wt2Hi,
                                                   unsigned short* __restrict__ Wt2Lo,
                                                   int hb,
                                                   const int* __restrict__ col,
                                                   int* __restrict__ cnt,
                                                   int* __restrict__ rank, int E) {
    if (blockIdx.x < (unsigned)hb) {
        int e = blockIdx.x * 256 + threadIdx.x;
        if (e < E) rank[e] = atomicAdd(&cnt[col[e]], 1);
    } else {
        int i = (blockIdx.x - hb) * 256 + threadIdx.x;   // 0..32767
        const float* src   = (i < 16384) ? W1    : W2;
        unsigned short* dh = (i < 16384) ? Wt1Hi : Wt2Hi;
        unsigned short* dl = (i < 16384) ? Wt1Lo : Wt2Lo;
        int idx = i & 16383;
        int k = idx >> 7, n = idx & 127;
        float v = src[idx];                        // W[k][n]
        unsigned short hbv = f2bf_rne(v);
        float hf = __uint_as_float((unsigned int)hbv << 16);
        unsigned short lb = f2bf_rne(v - hf);
        dh[n * H_DIM + k] = hbv;
        dl[n * H_DIM + k] = lb;
    }
}

// ---------------------------------------------------------------------------
__global__ __launch_bounds__(256) void scan_phase1(const int* __restrict__ cnt,
                                                   int* __restrict__ blockSums,
                                                   float* __restrict__ dinv, int N) {
    __shared__ int red[256];
    int base = blockIdx.x * 1024;
    int t = threadIdx.x;
    int s = 0;
    for (int i = 0; i < 4; ++i) {
        int idx = base + t * 4 + i;
        if (idx < N) {
            int cv = cnt[idx];
            s += cv;
            dinv[idx] = rsqrtf((float)cv + 1.0f);   // deg>=1 (self loop)
        }
    }
    red[t] = s;
    __syncthreads();
    for (int d = 128; d > 0; d >>= 1) {
        if (t < d) red[t] += red[t + d];
        __syncthreads();
    }
    if (t == 0) blockSums[blockIdx.x] = red[0];
}

// ---------------------------------------------------------------------------
__global__ __launch_bounds__(256) void scan_phase23(const int* __restrict__ cnt,
                                                    const int* __restrict__ blockSums,
                                                    int* __restrict__ offs, int N, int B) {
    __shared__ int red[256];
    __shared__ int bsum[256];
    int base = blockIdx.x * 1024;
    int t = threadIdx.x;

    bsum[t] = (t < B && t < (int)blockIdx.x) ? blockSums[t] : 0;

    int v[4];
    int s = 0;
    for (int i = 0; i < 4; ++i) {
        int idx = base + t * 4 + i;
        v[i] = (idx < N) ? cnt[idx] : 0;
        s += v[i];
    }
    red[t] = s;
    __syncthreads();
    for (int d = 128; d > 0; d >>= 1) {
        if (t < d) bsum[t] += bsum[t + d];
        __syncthreads();
    }
    for (int d = 1; d < 256; d <<= 1) {
        int x = (t >= d) ? red[t - d] : 0;
        __syncthreads();
        red[t] += x;
        __syncthreads();
    }
    int run = bsum[0] + ((t == 0) ? 0 : red[t - 1]);
    for (int i = 0; i < 4; ++i) {
        int idx = base + t * 4 + i;
        if (idx < N) { offs[idx] = run; run += v[i]; }
    }
    if ((int)blockIdx.x == B - 1 && t == 255) offs[N] = run;   // == E
}

// ---------------------------------------------------------------------------
// FUSED scatter + layer-1 GEMM (f32 X read + in-register hi/lo split).
__global__ __launch_bounds__(256) void scatter_gemm1(
        const int* __restrict__ row, const int* __restrict__ col,
        const int* __restrict__ rank, const float* __restrict__ dinv,
        const int* __restrict__ offs, int2* __restrict__ csr, int E, int sb,
        const float* __restrict__ Xf,
        const unsigned short* __restrict__ WtHi, const unsigned short* __restrict__ WtLo,
        unsigned short* __restrict__ Yb, int N) {
    if (blockIdx.x < (unsigned)sb) {
        int e = blockIdx.x * 256 + threadIdx.x;
        if (e >= E) return;
        int r = row[e], c = col[e], rk = rank[e];
        int pos = offs[c] + rk;
        int2 p; p.x = r; p.y = __float_as_int(dinv[r] * dinv[c]);
        csr[pos] = p;
        return;
    }
    int blk  = blockIdx.x - sb;
    int lane = threadIdx.x & 63;
    int wv   = threadIdx.x >> 6;
    int m16  = lane & 15;
    int quad = lane >> 4;
    int nodeBase = blk * 32;

    f32x4 acc[2][2] = {};

    #pragma unroll
    for (int kt = 0; kt < 4; ++kt) {
        int k0 = kt * 32 + quad * 8;

        ushort8 aHi[2], aLo[2];
        #pragma unroll
        for (int mi = 0; mi < 2; ++mi) {
            int node = nodeBase + mi * 16 + m16;
            if (node >= N) node = N - 1;
            const float* p = Xf + (size_t)node * H_DIM + k0;
            f32x4 u = *(const f32x4*)p;
            f32x4 w = *(const f32x4*)(p + 4);
            float vv[8] = {u.x, u.y, u.z, u.w, w.x, w.y, w.z, w.w};
            #pragma unroll
            for (int j = 0; j < 8; ++j) {
                unsigned short hbv = f2bf_rne(vv[j]);
                aHi[mi][j] = hbv;
                aLo[mi][j] = f2bf_rne(vv[j] - __uint_as_float((unsigned int)hbv << 16));
            }
        }

        ushort8 bHi[2], bLo[2];
        #pragma unroll
        for (int ni = 0; ni < 2; ++ni) {
            int n = (wv * 2 + ni) * 16 + m16;
            size_t off = (size_t)n * H_DIM + k0;
            bHi[ni] = *(const ushort8*)(WtHi + off);
            bLo[ni] = *(const ushort8*)(WtLo + off);
        }

        #pragma unroll
        for (int mi = 0; mi < 2; ++mi)
            #pragma unroll
            for (int ni = 0; ni < 2; ++ni) {
                acc[mi][ni] = __builtin_amdgcn_mfma_f32_16x16x32_bf16(
                    __builtin_bit_cast(bf16x8, aHi[mi]),
                    __builtin_bit_cast(bf16x8, bHi[ni]), acc[mi][ni], 0, 0, 0);
                acc[mi][ni] = __builtin_amdgcn_mfma_f32_16x16x32_bf16(
                    __builtin_bit_cast(bf16x8, aLo[mi]),
                    __builtin_bit_cast(bf16x8, bHi[ni]), acc[mi][ni], 0, 0, 0);
                acc[mi][ni] = __builtin_amdgcn_mfma_f32_16x16x32_bf16(
                    __builtin_bit_cast(bf16x8, aHi[mi]),
                    __builtin_bit_cast(bf16x8, bLo[ni]), acc[mi][ni], 0, 0, 0);
            }
    }

    #pragma unroll
    for (int mi = 0; mi < 2; ++mi)
        #pragma unroll
        for (int r = 0; r < 4; ++r) {
            int node = nodeBase + mi * 16 + quad * 4 + r;
            if (node < N) {
                #pragma unroll
                for (int ni = 0; ni < 2; ++ni) {
                    int c = (wv * 2 + ni) * 16 + m16;
                    Yb[(size_t)node * H_DIM + c] = f2bf_rne(acc[mi][ni][r]);
                }
            }
        }
}

// ---------------------------------------------------------------------------
// FUSED layer-1 aggregation + layer-2 GEMM, dwordx4 gather engine.
__global__ __launch_bounds__(256) void agg1_gemm2(
        const unsigned short* __restrict__ XWb,
        const float* __restrict__ dinv,
        const int2* __restrict__ csr,
        const int* __restrict__ offs,
        const float* __restrict__ bias,
        const unsigned short* __restrict__ WtHi,   // W2 hi (transposed)
        const unsigned short* __restrict__ WtLo,   // W2 lo
        unsigned short* __restrict__ Yb,           // XW2 out
        int N) {
    __shared__ __align__(16) unsigned short hrow[16][136];   // +8 pad
    int lane = threadIdx.x & 63;
    int wv   = threadIdx.x >> 6;
    int sub  = lane >> 4;
    int fl   = lane & 15;
    int nodeBase = blockIdx.x * 16;
    const int4* XW16 = (const int4*)XWb;
    float4 b0 = ((const float4*)bias)[fl * 2];
    float4 b1 = ((const float4*)bias)[fl * 2 + 1];

    for (int i = 0; i < 4; ++i) {
        int c = nodeBase + wv * 4 + i;
        float ax[4] = {}, ay[4] = {};
        if (c < N) {
            int start = offs[c], end = offs[c + 1];
            float dc = dinv[c];
            gather_node(XW16, csr, start, end, c, dc * dc, sub, fl, lane, ax, ay);
            ax[0] = fmaxf(ax[0] + b0.x, 0.f); ay[0] = fmaxf(ay[0] + b0.y, 0.f);
            ax[1] = fmaxf(ax[1] + b0.z, 0.f); ay[1] = fmaxf(ay[1] + b0.w, 0.f);
            ax[2] = fmaxf(ax[2] + b1.x, 0.f); ay[2] = fmaxf(ay[2] + b1.y, 0.f);
            ax[3] = fmaxf(ax[3] + b1.z, 0.f); ay[3] = fmaxf(ay[3] + b1.w, 0.f);
        }
        if (sub == 0) {                        // 16 lanes stage the bf16 row
            unsigned int o[4];
            #pragma unroll
            for (int q = 0; q < 4; ++q)
                o[q] = (unsigned int)f2bf_rne(ax[q]) | ((unsigned int)f2bf_rne(ay[q]) << 16);
            *(int4*)&hrow[wv * 4 + i][fl * 8] = *(const int4*)o;
        }
    }
    __syncthreads();

    // ---- layer-2 GEMM: hrow[16][128] @ W2[128][128]
    int m16  = lane & 15;
    int quad = lane >> 4;
    f32x4 acc[2] = {};
    #pragma unroll
    for (int kt = 0; kt < 4; ++kt) {
        int k0 = kt * 32 + quad * 8;
        ushort8 a = *(const ushort8*)&hrow[m16][k0];
        #pragma unroll
        for (int ni = 0; ni < 2; ++ni) {
            int n = (wv * 2 + ni) * 16 + m16;
            size_t off = (size_t)n * H_DIM + k0;
            ushort8 bHi = *(const ushort8*)(WtHi + off);
            ushort8 bLo = *(const ushort8*)(WtLo + off);
            acc[ni] = __builtin_amdgcn_mfma_f32_16x16x32_bf16(
                __builtin_bit_cast(bf16x8, a),
                __builtin_bit_cast(bf16x8, bHi), acc[ni], 0, 0, 0);
            acc[ni] = __builtin_amdgcn_mfma_f32_16x16x32_bf16(
                __builtin_bit_cast(bf16x8, a),
                __builtin_bit_cast(bf16x8, bLo), acc[ni], 0, 0, 0);
        }
    }
    #pragma unroll
    for (int r = 0; r < 4; ++r) {
        int node = nodeBase + quad * 4 + r;
        if (node < N) {
            #pragma unroll
            for (int ni = 0; ni < 2; ++ni) {
                int cc = (wv * 2 + ni) * 16 + m16;
                Yb[(size_t)node * H_DIM + cc] = f2bf_rne(acc[ni][r]);
            }
        }
    }
}

// ---------------------------------------------------------------------------
// Layer-2 aggregation + fused pooling, dwordx4 gather engine.
__global__ __launch_bounds__(256) void agg_pool(const unsigned short* __restrict__ XWb,
                                                const float* __restrict__ dinv,
                                                const int2* __restrict__ csr,
                                                const int* __restrict__ offs,
                                                const float* __restrict__ bias,
                                                const int* __restrict__ batch,
                                                float* __restrict__ pooledSum, int N) {
    int wave = (blockIdx.x * 256 + threadIdx.x) >> 6;
    int lane = threadIdx.x & 63;
    int wv   = threadIdx.x >> 6;
    int sub  = lane >> 4;
    int fl   = lane & 15;
    bool active = wave < N;

    float ax[4] = {}, ay[4] = {};
    int c = wave;
    if (active) {
        int start = offs[c], end = offs[c + 1];
        float dc = dinv[c];
        gather_node((const int4*)XWb, csr, start, end, c, dc * dc, sub, fl, lane, ax, ay);
        float4 b0 = ((const float4*)bias)[fl * 2];
        float4 b1 = ((const float4*)bias)[fl * 2 + 1];
        ax[0] = fmaxf(ax[0] + b0.x, 0.f); ay[0] = fmaxf(ay[0] + b0.y, 0.f);
        ax[1] = fmaxf(ax[1] + b0.z, 0.f); ay[1] = fmaxf(ay[1] + b0.w, 0.f);
        ax[2] = fmaxf(ax[2] + b1.x, 0.f); ay[2] = fmaxf(ay[2] + b1.y, 0.f);
        ax[3] = fmaxf(ax[3] + b1.z, 0.f); ay[3] = fmaxf(ay[3] + b1.w, 0.f);
    }

    __shared__ float lacc[4][H_DIM];
    __shared__ int lg[4];
    if (lane == 0) lg[wv] = active ? batch[c] : -1;
    if (sub == 0) {                           // 16 lanes write 8 floats each
        float4 f0; f0.x = ax[0]; f0.y = ay[0]; f0.z = ax[1]; f0.w = ay[1];
        float4 f1; f1.x = ax[2]; f1.y = ay[2]; f1.z = ax[3]; f1.w = ay[3];
        ((float4*)&lacc[wv][fl * 8])[0] = f0;
        ((float4*)&lacc[wv][fl * 8])[1] = f1;
    }
    __syncthreads();
    int t = threadIdx.x;
    if (t < H_DIM) {
        float s = 0.f; int cur = -1;
        #pragma unroll
        for (int w = 0; w < 4; ++w) {
            int g = lg[w];
            if (g < 0) continue;
            if (g != cur) {
                if (cur >= 0) atomicAdd(&pooledSum[cur * H_DIM + t], s);
                s = 0.f; cur = g;
            }
            s += lacc[w][t];
        }
        if (cur >= 0) atomicAdd(&pooledSum[cur * H_DIM + t], s);
    }
}

// ---------------------------------------------------------------------------
// Head: count via binary search on sorted batch, mean, FC, log-softmax.
__global__ __launch_bounds__(64) void head_kernel(const float* __restrict__ pooledSum,
                                                  const int* __restrict__ batch,
                                                  const float* __restrict__ Wfc,
                                                  const float* __restrict__ bfc,
                                                  float* __restrict__ out, int N) {
    __shared__ float sl[OUT_DIM + 2];
    __shared__ int bounds[2];
    int g = blockIdx.x;
    int j = threadIdx.x;
    if (j < 2) {
        int v = g + j;
        int lo = 0, hi = N;
        while (lo < hi) {
            int mid = (lo + hi) >> 1;
            if (batch[mid] < v) lo = mid + 1; else hi = mid;
        }
        bounds[j] = lo;
    }
    __syncthreads();
    int cnt = bounds[1] - bounds[0];
    float inv = 1.0f / (float)(cnt > 0 ? cnt : 1);
    if (j < OUT_DIM) {
        float acc = 0.f;
        const float* p = pooledSum + g * H_DIM;
        for (int k = 0; k < H_DIM; ++k) acc += p[k] * Wfc[k * OUT_DIM + j];
        sl[j] = acc * inv + bfc[j];
    }
    __syncthreads();
    if (j == 0) {
        float m = sl[0];
        for (int i = 1; i < OUT_DIM; ++i) m = fmaxf(m, sl[i]);
        float s = 0.f;
        for (int i = 0; i < OUT_DIM; ++i) s += expf(sl[i] - m);
        sl[OUT_DIM] = m + logf(s);
    }
    __syncthreads();
    if (j < OUT_DIM) out[g * OUT_DIM + j] = sl[j] - sl[OUT_DIM];
}

// ---------------------------------------------------------------------------
extern "C" void kernel_launch(void* const* d_in, const int* in_sizes, int n_in,
                              void* d_out, int out_size, void* d_ws, size_t ws_size,
                              hipStream_t stream) {
    const float* x     = (const float*)d_in[0];
    const int*   ei    = (const int*)  d_in[1];
    const int*   batch = (const int*)  d_in[2];
    const float* W1    = (const float*)d_in[3];
    const float* b1    = (const float*)d_in[4];
    const float* W2    = (const float*)d_in[5];
    const float* b2    = (const float*)d_in[6];
    const float* Wfc   = (const float*)d_in[7];
    const float* bfc   = (const float*)d_in[8];
    float* out = (float*)d_out;

    int N = in_sizes[2];
    int E = in_sizes[1] / 2;
    int G = out_size / OUT_DIM;
    const int* row = ei;
    const int* col = ei + E;

    // Workspace layout (ONE memset zeroes cnt+pooledSum, adjacent):
    // cnt[nAlign] | pooledSum[G*128] | offs[nAlign] | rank[E] | dinv[nAlign]
    //   | csr[E] int2 | Xb[N*128] us | Hb[N*128] us
    //   | blockSums[256] | Wt{1,2}{Hi,Lo}[16384] us
    char* wsb = (char*)d_ws;
    size_t nAlign = (size_t)((N + 256) / 256) * 256;   // >= N+1
    size_t eAlign = (size_t)((E + 255) / 256) * 256;
    int*   cnt       = (int*)wsb;
    float* pooledSum = (float*)(cnt + nAlign);
    int*   offs      = (int*)(pooledSum + (size_t)G * H_DIM);
    int*   rank      = offs + nAlign;
    float* dinv      = (float*)(rank + eAlign);
    int2*  csr       = (int2*)(dinv + nAlign);
    unsigned short* Xb = (unsigned short*)(csr + E);
    unsigned short* Hb = Xb + (size_t)N * H_DIM;
    int* blockSums = (int*)(Hb + (size_t)N * H_DIM);
    unsigned short* Wt1Hi = (unsigned short*)(blockSums + 256);
    unsigned short* Wt1Lo = Wt1Hi + H_DIM * H_DIM;
    unsigned short* Wt2Hi = Wt1Lo + H_DIM * H_DIM;
    unsigned short* Wt2Lo = Wt2Hi + H_DIM * H_DIM;

    int scanBlocks = (N + 1023) / 1024;   // 40 for N=40000 (<=256 supported)
    int histBlocks = (E + 255) / 256;
    int gemmBlocks = (N + 31) / 32;       // 32 nodes/block (layer 1)

    // ---- One memset for cnt + pooledSum (adjacent)
    hipMemsetAsync(cnt, 0, (nAlign + (size_t)G * H_DIM) * sizeof(int), stream);

    // ---- Fused histogram (FIRST) + W-split
    prep_kernel<<<histBlocks + 128, 256, 0, stream>>>(
        W1, W2, Wt1Hi, Wt1Lo, Wt2Hi, Wt2Lo, histBlocks, col, cnt, rank, E);

    // ---- 2-dispatch scan
    scan_phase1<<<scanBlocks, 256, 0, stream>>>(cnt, blockSums, dinv, N);
    scan_phase23<<<scanBlocks, 256, 0, stream>>>(cnt, blockSums, offs, N, scanBlocks);

    // ---- FUSED scatter + layer-1 GEMM -> Xb
    scatter_gemm1<<<histBlocks + gemmBlocks, 256, 0, stream>>>(
        row, col, rank, dinv, offs, csr, E, histBlocks,
        x, Wt1Hi, Wt1Lo, Xb, N);

    // ---- FUSED layer-1 aggregation + layer-2 GEMM -> Hb (holds XW2 now)
    int ag1Blocks = (N + 15) / 16;        // 16 nodes/block
    agg1_gemm2<<<ag1Blocks, 256, 0, stream>>>(Xb, dinv, csr, offs, b1,
                                              Wt2Hi, Wt2Lo, Hb, N);

    // ---- Layer-2 aggregation + fused pooling
    int aggBlocks = (N + 3) / 4;          // 4 waves/block, 1 wave/node
    agg_pool<<<aggBlocks, 256, 0, stream>>>(Hb, dinv, csr, offs, b2,
                                            batch, pooledSum, N);

    // ---- Head (count/divide folded in)
    head_kernel<<<G, 64, 0, stream>>>(pooledSum, batch, Wfc, bfc, out, N);
}